// Round 3
// baseline (415.094 us; speedup 1.0000x reference)
//
#include <hip/hip_runtime.h>

#define BLK 256
#define DD  48
#define NB  16
#define STR 257   // odd stride: (col+row)%32 banking -> <=3-way on write, 2-way (free) on read

__device__ __forceinline__ float2 cmul(float2 a, float2 b) {
    return make_float2(fmaf(a.x, b.x, -a.y * b.y),
                       fmaf(a.x, b.y,  a.y * b.x));
}
__device__ __forceinline__ float2 cmadd(float2 a, float2 b, float2 c) {
    // a*b + c (complex)
    return make_float2(fmaf(a.x, b.x, fmaf(-a.y, b.y, c.x)),
                       fmaf(a.x, b.y, fmaf( a.y, b.x, c.y)));
}

__global__ __launch_bounds__(BLK) void qlayer_kernel(
    const float* __restrict__ rho_real,
    const float* __restrict__ rho_imag,
    const float* __restrict__ x,
    const float* __restrict__ w,
    const float* __restrict__ theta,
    float* __restrict__ out,
    long long n,            // number of elements B
    long long out_floats)   // d_out capacity in floats (expected 4*n: REAL part only)
{
    __shared__ float2 swt[DD];          // {theta, w}
    __shared__ float  sphi[DD * STR];   // transposed phi tile: [j][thread]

    const int tid = threadIdx.x;
    const long long blockBase = (long long)blockIdx.x * BLK;
    const long long xcount = n * DD;

    if (tid < DD) swt[tid] = make_float2(theta[tid], w[tid]);
    __syncthreads();

    // --- Stage phi = theta + x*w into LDS, transposed ---
    // Global reads lane-consecutive (coalesced); LDS write bank = (col+row)%32.
    const long long xbase = blockBase * DD;
    int row = tid / DD;             // element-within-tile
    int col = tid - row * DD;       // phi index j
    #pragma unroll 8
    for (int i = 0; i < DD; ++i) {
        long long gidx = xbase + tid + i * BLK;
        float xv = (gidx < xcount) ? x[gidx] : 0.0f;   // guard: no OOB possible
        float2 wt = swt[col];
        sphi[col * STR + row] = fmaf(xv, wt.y, wt.x);
        // advance by 256 elements: 256 = 5*48 + 16
        col += 16; row += 5;
        if (col >= DD) { col -= DD; ++row; }
    }
    __syncthreads();

    const long long b = blockBase + tid;
    if (b >= n) return;   // partial-tile guard (no-op when B % 256 == 0)

    // --- Load rho (coalesced float4) ---
    float4 rr = reinterpret_cast<const float4*>(rho_real)[b];
    float4 ri = reinterpret_cast<const float4*>(rho_imag)[b];
    float2 r00 = make_float2(rr.x, ri.x);
    float2 r01 = make_float2(rr.y, ri.y);
    float2 r10 = make_float2(rr.z, ri.z);
    float2 r11 = make_float2(rr.w, ri.w);

    // --- 16 sequential SU(2) conjugations ---
    #pragma unroll
    for (int k = 0; k < NB; ++k) {
        float p0 = sphi[(3 * k + 0) * STR + tid];
        float p1 = sphi[(3 * k + 1) * STR + tid];
        float p2 = sphi[(3 * k + 2) * STR + tid];
        float a  = 0.5f * p0;
        float bb = 0.5f * (p1 + p2);
        float cc = 0.5f * (p1 - p2);
        float sa, ca, sb, cb, sc, ccv;
        __sincosf(a,  &sa, &ca);
        __sincosf(bb, &sb, &cb);
        __sincosf(cc, &sc, &ccv);

        // U = [[ca*e^{ib}, -sa*e^{ic}], [sa*e^{-ic}, ca*e^{-ib}]]
        float cacb = ca * cb, casb = ca * sb;
        float sacc = sa * ccv, sasc = sa * sc;
        float2 u00 = make_float2( cacb,  casb);
        float2 u01 = make_float2(-sacc, -sasc);
        float2 u10 = make_float2( sacc, -sasc);
        float2 u11 = make_float2( cacb, -casb);

        // T = U * rho
        float2 t00 = cmadd(u01, r10, cmul(u00, r00));
        float2 t01 = cmadd(u01, r11, cmul(u00, r01));
        float2 t10 = cmadd(u11, r10, cmul(u10, r00));
        float2 t11 = cmadd(u11, r11, cmul(u10, r01));

        // rho = T * U^H : r_ij = sum_m t_im * conj(u_jm)
        float2 cu00 = make_float2(u00.x, -u00.y);
        float2 cu01 = make_float2(u01.x, -u01.y);
        float2 cu10 = make_float2(u10.x, -u10.y);
        float2 cu11 = make_float2(u11.x, -u11.y);
        r00 = cmadd(t01, cu01, cmul(t00, cu00));
        r01 = cmadd(t01, cu11, cmul(t00, cu10));
        r10 = cmadd(t11, cu01, cmul(t10, cu00));
        r11 = cmadd(t11, cu11, cmul(t10, cu10));
    }

    // --- Store REAL part only: [B,2,2] float32, one float4 per element ---
    if (4 * b + 4 <= out_floats) {
        float4 o = make_float4(r00.x, r01.x, r10.x, r11.x);
        reinterpret_cast<float4*>(out)[b] = o;
    } else {
        float vals[4] = {r00.x, r01.x, r10.x, r11.x};
        for (int j = 0; j < 4; ++j) {
            long long o = 4 * b + j;
            if (o < out_floats) out[o] = vals[j];
        }
    }
}

extern "C" void kernel_launch(void* const* d_in, const int* in_sizes, int n_in,
                              void* d_out, int out_size, void* d_ws, size_t ws_size,
                              hipStream_t stream) {
    const float* rho_real = (const float*)d_in[0];
    const float* rho_imag = (const float*)d_in[1];
    const float* x        = (const float*)d_in[2];
    const float* w        = (const float*)d_in[3];
    const float* theta    = (const float*)d_in[4];
    float* out = (float*)d_out;

    // rho_real is [B,2,2] -> B = count/4. Cross-check with x: B = in_sizes[2]/48.
    long long nB = (long long)in_sizes[0] / 4;
    long long nX = (long long)in_sizes[2] / DD;
    long long n  = nB < nX ? nB : nX;    // defensive: never exceed either buffer
    if (n <= 0) return;

    int grid = (int)((n + BLK - 1) / BLK);
    qlayer_kernel<<<dim3(grid), dim3(BLK), 0, stream>>>(
        rho_real, rho_imag, x, w, theta, out, n, (long long)out_size);
}

// Round 4
// 316.982 us; speedup vs baseline: 1.3095x; 1.3095x over previous
//
#include <hip/hip_runtime.h>

#define BLK 256
#define DD  48
#define NB  16

__device__ __forceinline__ float2 cmul(float2 a, float2 b) {
    return make_float2(fmaf(a.x, b.x, -a.y * b.y),
                       fmaf(a.x, b.y,  a.y * b.x));
}
__device__ __forceinline__ float2 cmadd(float2 a, float2 b, float2 c) {
    // a*b + c (complex)
    return make_float2(fmaf(a.x, b.x, fmaf(-a.y, b.y, c.x)),
                       fmaf(a.x, b.y, fmaf( a.y, b.x, c.y)));
}

__global__ __launch_bounds__(BLK) void qlayer_kernel(
    const float* __restrict__ rho_real,
    const float* __restrict__ rho_imag,
    const float* __restrict__ x,
    const float* __restrict__ w,
    const float* __restrict__ theta,
    float* __restrict__ out,
    long long n,            // number of elements B
    long long out_floats)   // d_out capacity in floats (4*n: REAL part only)
{
    const long long b = (long long)blockIdx.x * BLK + threadIdx.x;
    if (b >= n) return;

    // --- Load rho (coalesced float4) ---
    float4 rr = reinterpret_cast<const float4*>(rho_real)[b];
    float4 ri = reinterpret_cast<const float4*>(rho_imag)[b];
    float2 r00 = make_float2(rr.x, ri.x);
    float2 r01 = make_float2(rr.y, ri.y);
    float2 r10 = make_float2(rr.z, ri.z);
    float2 r11 = make_float2(rr.w, ri.w);

    // x row for this element: 48 floats, 192 B, float4-aligned.
    // Per-lane contiguous float4 loads; 64 lanes stride 192 B -> all lines
    // land in L1 and every byte is used (x read exactly once from HBM/L2).
    const float4* __restrict__ xv = reinterpret_cast<const float4*>(x + b * DD);

    // --- 16 sequential SU(2) conjugations, 4 groups of 4 rotations ---
    #pragma unroll
    for (int g = 0; g < 4; ++g) {
        float4 q0 = xv[3 * g + 0];
        float4 q1 = xv[3 * g + 1];
        float4 q2 = xv[3 * g + 2];
        float xs[12] = {q0.x, q0.y, q0.z, q0.w,
                        q1.x, q1.y, q1.z, q1.w,
                        q2.x, q2.y, q2.z, q2.w};
        #pragma unroll
        for (int r = 0; r < 4; ++r) {
            const int j = 12 * g + 3 * r;   // compile-time constant -> s_load w/theta
            float p0 = fmaf(xs[3 * r + 0], w[j + 0], theta[j + 0]);
            float p1 = fmaf(xs[3 * r + 1], w[j + 1], theta[j + 1]);
            float p2 = fmaf(xs[3 * r + 2], w[j + 2], theta[j + 2]);

            float a  = 0.5f * p0;
            float bb = 0.5f * (p1 + p2);
            float cc = 0.5f * (p1 - p2);
            float sa, ca, sb, cb, sc, ccv;
            __sincosf(a,  &sa, &ca);
            __sincosf(bb, &sb, &cb);
            __sincosf(cc, &sc, &ccv);

            // U = [[ca*e^{ib}, -sa*e^{ic}], [sa*e^{-ic}, ca*e^{-ib}]]
            float cacb = ca * cb, casb = ca * sb;
            float sacc = sa * ccv, sasc = sa * sc;
            float2 u00 = make_float2( cacb,  casb);
            float2 u01 = make_float2(-sacc, -sasc);
            float2 u10 = make_float2( sacc, -sasc);
            float2 u11 = make_float2( cacb, -casb);

            // T = U * rho
            float2 t00 = cmadd(u01, r10, cmul(u00, r00));
            float2 t01 = cmadd(u01, r11, cmul(u00, r01));
            float2 t10 = cmadd(u11, r10, cmul(u10, r00));
            float2 t11 = cmadd(u11, r11, cmul(u10, r01));

            // rho = T * U^H : r_ij = sum_m t_im * conj(u_jm)
            float2 cu00 = make_float2(u00.x, -u00.y);
            float2 cu01 = make_float2(u01.x, -u01.y);
            float2 cu10 = make_float2(u10.x, -u10.y);
            float2 cu11 = make_float2(u11.x, -u11.y);
            r00 = cmadd(t01, cu01, cmul(t00, cu00));
            r01 = cmadd(t01, cu11, cmul(t00, cu10));
            r10 = cmadd(t11, cu01, cmul(t10, cu00));
            r11 = cmadd(t11, cu11, cmul(t10, cu10));
        }
    }

    // --- Store REAL part only: [B,2,2] float32, one float4 per element ---
    if (4 * b + 4 <= out_floats) {
        reinterpret_cast<float4*>(out)[b] = make_float4(r00.x, r01.x, r10.x, r11.x);
    } else {
        float vals[4] = {r00.x, r01.x, r10.x, r11.x};
        for (int j = 0; j < 4; ++j) {
            long long o = 4 * b + j;
            if (o < out_floats) out[o] = vals[j];
        }
    }
}

extern "C" void kernel_launch(void* const* d_in, const int* in_sizes, int n_in,
                              void* d_out, int out_size, void* d_ws, size_t ws_size,
                              hipStream_t stream) {
    const float* rho_real = (const float*)d_in[0];
    const float* rho_imag = (const float*)d_in[1];
    const float* x        = (const float*)d_in[2];
    const float* w        = (const float*)d_in[3];
    const float* theta    = (const float*)d_in[4];
    float* out = (float*)d_out;

    long long nB = (long long)in_sizes[0] / 4;
    long long nX = (long long)in_sizes[2] / DD;
    long long n  = nB < nX ? nB : nX;
    if (n <= 0) return;

    int grid = (int)((n + BLK - 1) / BLK);
    qlayer_kernel<<<dim3(grid), dim3(BLK), 0, stream>>>(
        rho_real, rho_imag, x, w, theta, out, n, (long long)out_size);
}

// Round 5
// 311.004 us; speedup vs baseline: 1.3347x; 1.0192x over previous
//
#include <hip/hip_runtime.h>

#define BLK 256
#define DD  48

// rho = a0*I + v.sigma  (a0, v complex). Conjugation by
// U = Rz(-p1) Ry(p0) Rz(-p2)  (SU(2) Euler match, verified vs reference U)
// leaves a0 invariant and rotates v by the same SO(3) Euler product,
// applied rightmost-first: z(-p2), then y(+p0), then z(-p1).
__global__ __launch_bounds__(BLK) void qlayer_kernel(
    const float* __restrict__ rho_real,
    const float* __restrict__ rho_imag,
    const float* __restrict__ x,
    const float* __restrict__ w,
    const float* __restrict__ theta,
    float* __restrict__ out,
    long long n,            // number of elements B
    long long out_floats)   // d_out capacity in floats (4*n: REAL part only)
{
    const long long b = (long long)blockIdx.x * BLK + threadIdx.x;
    if (b >= n) return;

    // --- Load rho (coalesced float4) ---
    float4 rr = reinterpret_cast<const float4*>(rho_real)[b];  // r00 r01 r10 r11 (re)
    float4 ri = reinterpret_cast<const float4*>(rho_imag)[b];  // (im)

    // --- Bloch decomposition (complex coefficients) ---
    // a0 = (r00+r11)/2  (invariant; imag part never needed for output)
    float a0r = 0.5f * (rr.x + rr.w);
    // v1 = (r01+r10)/2
    float v1r = 0.5f * (rr.y + rr.z), v1i = 0.5f * (ri.y + ri.z);
    // v2 = i*(r01-r10)/2
    float v2r = 0.5f * (ri.z - ri.y), v2i = 0.5f * (rr.y - rr.z);
    // v3 = (r00-r11)/2
    float v3r = 0.5f * (rr.x - rr.w), v3i = 0.5f * (ri.x - ri.w);

    // x row: 48 floats, 192 B, float4-aligned; lines fully consumed via L1.
    const float4* __restrict__ xv = reinterpret_cast<const float4*>(x + b * DD);

    #pragma unroll
    for (int g = 0; g < 4; ++g) {
        float4 q0 = xv[3 * g + 0];
        float4 q1 = xv[3 * g + 1];
        float4 q2 = xv[3 * g + 2];
        float xs[12] = {q0.x, q0.y, q0.z, q0.w,
                        q1.x, q1.y, q1.z, q1.w,
                        q2.x, q2.y, q2.z, q2.w};
        #pragma unroll
        for (int r = 0; r < 4; ++r) {
            const int j = 12 * g + 3 * r;   // compile-time const -> scalar w/theta loads
            float p0 = fmaf(xs[3 * r + 0], w[j + 0], theta[j + 0]);
            float p1 = fmaf(xs[3 * r + 1], w[j + 1], theta[j + 1]);
            float p2 = fmaf(xs[3 * r + 2], w[j + 2], theta[j + 2]);

            float s0, c0, s1, c1, s2, c2;
            __sincosf(p0, &s0, &c0);
            __sincosf(p1, &s1, &c1);
            __sincosf(p2, &s2, &c2);

            // Rz(-p2) on (v1,v2):  v1' = c2*v1 + s2*v2 ; v2' = c2*v2 - s2*v1
            float n1r = fmaf(c2, v1r,  s2 * v2r);
            float n1i = fmaf(c2, v1i,  s2 * v2i);
            float n2r = fmaf(c2, v2r, -s2 * v1r);
            float n2i = fmaf(c2, v2i, -s2 * v1i);
            // Ry(p0) on (v1,v3):   v1'' = c0*v1' + s0*v3 ; v3' = c0*v3 - s0*v1'
            float m1r = fmaf(c0, n1r,  s0 * v3r);
            float m1i = fmaf(c0, n1i,  s0 * v3i);
            float m3r = fmaf(c0, v3r, -s0 * n1r);
            float m3i = fmaf(c0, v3i, -s0 * n1i);
            // Rz(-p1) on (v1,v2):  v1''' = c1*v1'' + s1*v2' ; v2'' = c1*v2' - s1*v1''
            v1r = fmaf(c1, m1r,  s1 * n2r);
            v1i = fmaf(c1, m1i,  s1 * n2i);
            v2r = fmaf(c1, n2r, -s1 * m1r);
            v2i = fmaf(c1, n2i, -s1 * m1i);
            v3r = m3r;
            v3i = m3i;
        }
    }

    // --- Reassemble REAL parts only ---
    // Re r00 = a0r + v3r ; Re r01 = v1r + v2i ; Re r10 = v1r - v2i ; Re r11 = a0r - v3r
    if (4 * b + 4 <= out_floats) {
        reinterpret_cast<float4*>(out)[b] =
            make_float4(a0r + v3r, v1r + v2i, v1r - v2i, a0r - v3r);
    } else {
        float vals[4] = {a0r + v3r, v1r + v2i, v1r - v2i, a0r - v3r};
        for (int j = 0; j < 4; ++j) {
            long long o = 4 * b + j;
            if (o < out_floats) out[o] = vals[j];
        }
    }
}

extern "C" void kernel_launch(void* const* d_in, const int* in_sizes, int n_in,
                              void* d_out, int out_size, void* d_ws, size_t ws_size,
                              hipStream_t stream) {
    const float* rho_real = (const float*)d_in[0];
    const float* rho_imag = (const float*)d_in[1];
    const float* x        = (const float*)d_in[2];
    const float* w        = (const float*)d_in[3];
    const float* theta    = (const float*)d_in[4];
    float* out = (float*)d_out;

    long long nB = (long long)in_sizes[0] / 4;
    long long nX = (long long)in_sizes[2] / DD;
    long long n  = nB < nX ? nB : nX;
    if (n <= 0) return;

    int grid = (int)((n + BLK - 1) / BLK);
    qlayer_kernel<<<dim3(grid), dim3(BLK), 0, stream>>>(
        rho_real, rho_imag, x, w, theta, out, n, (long long)out_size);
}